// Round 10
// baseline (214.264 us; speedup 1.0000x reference)
//
#include <hip/hip_runtime.h>
#include <hip/hip_bf16.h>
#include <cstdint>
#include <cstddef>

#define D_MODEL 768
#define D_STATE 16
#define BB      4
#define LL      2048
#define M_TOT   (BB*LL)      // 8192
#define NCHUNK  64
#define LCH     (LL/NCHUNK)  // 32
#define N_DBC   896          // 768 delta + 16 B + 16 C + 96 pad
#define KC      768          // all GEMMs share K = D_MODEL
#define NTK     (KC/32)      // 24 K-steps

typedef __attribute__((ext_vector_type(8))) short bf16x8;
typedef __attribute__((ext_vector_type(4))) float f32x4;

__device__ __forceinline__ float clampf_(float x, float lo, float hi) {
    return fminf(fmaxf(x, lo), hi);
}
__device__ __forceinline__ float siluf_(float x) {
    return x / (1.f + __expf(-x));
}
// f32 -> bf16 round-to-nearest-even, as raw u16
__device__ __forceinline__ unsigned short f2bf(float f) {
    unsigned u = __float_as_uint(f);
    u += 0x7fffu + ((u >> 16) & 1u);
    return (unsigned short)(u >> 16);
}
__device__ __forceinline__ float bf2f(unsigned short u) {
    return __uint_as_float(((unsigned)u) << 16);
}
// async global->LDS, 16 bytes per lane; lds base must be wave-uniform
__device__ __forceinline__ void gload16(void* lds, const void* g) {
    __builtin_amdgcn_global_load_lds(
        (const __attribute__((address_space(1))) void*)g,
        (__attribute__((address_space(3))) void*)lds, 16, 0, 0);
}

// ---------------- prep kernels ----------------

__global__ __launch_bounds__(256) void k_convert_x(const float* __restrict__ x,
                                                   unsigned short* __restrict__ xb, int n4) {
    int i = blockIdx.x * 256 + threadIdx.x;
    if (i >= n4) return;
    float4 v = ((const float4*)x)[i];
    ushort4 o;
    o.x = f2bf(v.x); o.y = f2bf(v.y); o.z = f2bf(v.z); o.w = f2bf(v.w);
    ((ushort4*)xb)[i] = o;
}

__global__ __launch_bounds__(256) void k_prep_A(const float* __restrict__ A_log,
                                                float* __restrict__ A_cl, int n) {
    int i = blockIdx.x * 256 + threadIdx.x;
    if (i < n) A_cl[i] = clampf_(-__expf(A_log[i]), -5.f, -0.1f);
}

// transpose R x C f32 -> C x R bf16 (R,C multiples of 32); dst row stride = R
__global__ __launch_bounds__(256) void k_transpose_bf16(const float* __restrict__ src,
                                                        unsigned short* __restrict__ dst,
                                                        int R, int C) {
    __shared__ float tile[32][33];
    int tx = threadIdx.x & 31, ty = threadIdx.x >> 5;
    int c0 = blockIdx.x * 32, r0 = blockIdx.y * 32;
    #pragma unroll
    for (int rr = ty; rr < 32; rr += 8)
        tile[rr][tx] = src[(size_t)(r0 + rr) * C + c0 + tx];
    __syncthreads();
    #pragma unroll
    for (int rr = ty; rr < 32; rr += 8)
        dst[(size_t)(c0 + rr) * R + r0 + tx] = f2bf(tile[tx][rr]);
}

// rows 768..895 of WdBC: W_B^T, W_C^T, zero-pad
__global__ __launch_bounds__(256) void k_fill_bc(const float* __restrict__ W_B,
                                                 const float* __restrict__ W_C,
                                                 unsigned short* __restrict__ WdBC) {
    int idx = blockIdx.x * 256 + threadIdx.x;     // 128*768
    if (idx >= 128 * D_MODEL) return;
    int r = idx / D_MODEL + D_MODEL, k = idx % D_MODEL;
    unsigned short v = 0;
    if (r < D_MODEL + 16)       v = f2bf(W_B[k * 16 + (r - D_MODEL)]);
    else if (r < D_MODEL + 32)  v = f2bf(W_C[k * 16 + (r - D_MODEL - 16)]);
    WdBC[(size_t)r * D_MODEL + k] = v;
}

__global__ __launch_bounds__(256) void k_bias_dbc(const float* __restrict__ b_delta,
                                                  const float* __restrict__ b_B,
                                                  const float* __restrict__ b_C,
                                                  float* __restrict__ bias) {
    int i = blockIdx.x * 256 + threadIdx.x;
    if (i >= N_DBC) return;
    float v = 0.f;
    if (i < D_MODEL)            v = b_delta[i];
    else if (i < D_MODEL + 16)  v = b_B[i - D_MODEL];
    else if (i < D_MODEL + 32)  v = b_C[i - D_MODEL - 16];
    bias[i] = v;
}

// ---------------- main bf16 MFMA GEMM ----------------
// 3-buffer pipeline, counted vmcnt, compile-time buffer indices (unroll-by-3),
// round-7 fence discipline (lgkmcnt(0)+sched_barrier before read-done barrier),
// XCD swizzle. K fixed at 768.
template<int EPI>
__global__ __launch_bounds__(256) void k_gemm(const unsigned short* __restrict__ A,
                                              const unsigned short* __restrict__ Bt,
                                              const float* __restrict__ bias,
                                              int gx,
                                              float* __restrict__ out_f,
                                              float* __restrict__ out_f2,
                                              unsigned short* __restrict__ out_b0,
                                              unsigned short* __restrict__ out_b1) {
    __shared__ __align__(16) unsigned short As0[128 * 32], As1[128 * 32], As2[128 * 32];
    __shared__ __align__(16) unsigned short Bs0[128 * 32], Bs1[128 * 32], Bs2[128 * 32];
    const int tid = threadIdx.x;
    const int wave = tid >> 6, lane = tid & 63;
    const int wm = wave >> 1, wn = wave & 1;

    // bijective XCD swizzle (m204, r==0 case)
    const int nwg = gridDim.x;
    const int wg = blockIdx.x;
    int swz = wg;
    if ((nwg & 7) == 0) {
        const int q = nwg >> 3;
        swz = (wg & 7) * q + (wg >> 3);
    }
    const int bx = swz % gx, by = swz / gx;
    const int m0 = by * 128, n0 = bx * 128;
    const int lr = lane & 15, lk = (lane >> 4) * 8;

    // per-thread staging source pointers (2 chunks each for A and B)
    const int ci0 = wave * 64 + lane;            // chunk 0..255
    const int ci1 = 256 + ci0;                   // chunk 256..511
    const unsigned short* ga0 = &A [(size_t)(m0 + (ci0 >> 2)) * KC + (ci0 & 3) * 8];
    const unsigned short* ga1 = &A [(size_t)(m0 + (ci1 >> 2)) * KC + (ci1 & 3) * 8];
    const unsigned short* gb0 = &Bt[(size_t)(n0 + (ci0 >> 2)) * KC + (ci0 & 3) * 8];
    const unsigned short* gb1 = &Bt[(size_t)(n0 + (ci1 >> 2)) * KC + (ci1 & 3) * 8];
    const int ldsOff0 = (wave * 64) * 8;         // shorts, wave-uniform
    const int ldsOff1 = (256 + wave * 64) * 8;

    f32x4 acc[4][4] = {};

    auto stageT = [&](unsigned short* Ab, unsigned short* Bb, int kt) {
        gload16(&Ab[ldsOff0], ga0 + kt);
        gload16(&Ab[ldsOff1], ga1 + kt);
        gload16(&Bb[ldsOff0], gb0 + kt);
        gload16(&Bb[ldsOff1], gb1 + kt);
    };
    auto computeT = [&](const unsigned short* Ab, const unsigned short* Bb) {
        bf16x8 af[4], bfr[4];
        #pragma unroll
        for (int mt = 0; mt < 4; ++mt)
            af[mt] = *(const bf16x8*)&Ab[(wm * 64 + mt * 16 + lr) * 32 + lk];
        #pragma unroll
        for (int nt = 0; nt < 4; ++nt)
            bfr[nt] = *(const bf16x8*)&Bb[(wn * 64 + nt * 16 + lr) * 32 + lk];
        #pragma unroll
        for (int mt = 0; mt < 4; ++mt)
            #pragma unroll
            for (int nt = 0; nt < 4; ++nt)
                acc[mt][nt] = __builtin_amdgcn_mfma_f32_16x16x32_bf16(
                    af[mt], bfr[nt], acc[mt][nt], 0, 0, 0);
    };

    // prologue: tiles 0,1,2 in flight; wait for tile 0 (12 -> 8 outstanding)
    stageT(As0, Bs0, 0);
    stageT(As1, Bs1, 32);
    stageT(As2, Bs2, 64);
    asm volatile("s_waitcnt vmcnt(8)" ::: "memory");
    __builtin_amdgcn_sched_barrier(0);
    __builtin_amdgcn_s_barrier();

#define SUBSTEP(Ab, Bb, t) do {                                   \
        computeT(Ab, Bb);                                         \
        asm volatile("s_waitcnt lgkmcnt(0)" ::: "memory");        \
        __builtin_amdgcn_sched_barrier(0);                        \
        __builtin_amdgcn_s_barrier();                             \
        stageT(Ab, Bb, ((t) + 3) << 5);                           \
        asm volatile("s_waitcnt vmcnt(8)" ::: "memory");          \
        __builtin_amdgcn_sched_barrier(0);                        \
        __builtin_amdgcn_s_barrier();                             \
    } while (0)

    // steady state: 7 iterations x 3 sub-steps = tiles 0..20, staging 3..23
    for (int t = 0; t < NTK - 3; t += 3) {
        SUBSTEP(As0, Bs0, t);
        SUBSTEP(As1, Bs1, t + 1);
        SUBSTEP(As2, Bs2, t + 2);
    }
#undef SUBSTEP
    // tail: tiles 21,22,23; drain 4 -> 0
    computeT(As0, Bs0);
    asm volatile("s_waitcnt vmcnt(4)" ::: "memory");
    __builtin_amdgcn_sched_barrier(0);
    __builtin_amdgcn_s_barrier();
    computeT(As1, Bs1);
    asm volatile("s_waitcnt vmcnt(0)" ::: "memory");
    __builtin_amdgcn_sched_barrier(0);
    __builtin_amdgcn_s_barrier();
    computeT(As2, Bs2);

    #pragma unroll
    for (int mt = 0; mt < 4; ++mt) {
        int row = m0 + wm * 64 + mt * 16 + (lane >> 4) * 4;
        #pragma unroll
        for (int nt = 0; nt < 4; ++nt) {
            int col = n0 + wn * 64 + nt * 16 + (lane & 15);
            #pragma unroll
            for (int i = 0; i < 4; ++i) {
                int r = row + i;
                float v = acc[mt][nt][i] + bias[col];
                if (EPI == 0) {
                    float s = siluf_(v);
                    if (col < D_MODEL) out_b0[(size_t)r * D_MODEL + col] = f2bf(s);
                    else               out_b1[(size_t)r * D_MODEL + (col - D_MODEL)] = f2bf(s);
                } else if (EPI == 1) {
                    if (col < D_MODEL) {
                        float sp = (v > 20.f) ? v : log1pf(__expf(v));
                        out_b0[(size_t)r * D_MODEL + col] = f2bf(clampf_(sp + 1e-4f, 1e-4f, 1.f));
                    } else if (col < D_MODEL + 16) {
                        out_f[(size_t)r * D_STATE + (col - D_MODEL)] = v;
                    } else if (col < D_MODEL + 32) {
                        out_f2[(size_t)r * D_STATE + (col - D_MODEL - 16)] = v;
                    }
                } else {
                    out_f[(size_t)r * D_MODEL + col] = clampf_(v, -10.f, 10.f);
                }
            }
        }
    }
}

// ---------------- chunked selective scan ----------------
// pass A: per (b, chunk, d) local scan from h=0; emit h_end, Aprod
__global__ __launch_bounds__(256) void k_scanA(const unsigned short* __restrict__ dlt,
                                               const unsigned short* __restrict__ xm,
                                               const float* __restrict__ Bm,
                                               const float* __restrict__ A_cl,
                                               float* __restrict__ h_end,
                                               float* __restrict__ Aprod) {
    const int d = blockIdx.x * 256 + threadIdx.x;
    const int c = blockIdx.y, b = blockIdx.z;
    __shared__ float Bsh[LCH][D_STATE];
    const int rowbase = b * LL + c * LCH;
    for (int i = threadIdx.x; i < LCH * D_STATE; i += 256)
        ((float*)Bsh)[i] = Bm[(size_t)rowbase * D_STATE + i];
    __syncthreads();

    float Asv[16], h[16], ap[16];
    #pragma unroll
    for (int s = 0; s < 16; ++s) {
        Asv[s] = A_cl[s * D_MODEL + d];
        h[s] = 0.f; ap[s] = 1.f;
    }
    for (int tt = 0; tt < LCH; ++tt) {
        const size_t rowoff = (size_t)(rowbase + tt);
        float dltv = bf2f(dlt[rowoff * D_MODEL + d]);
        float xv   = bf2f(xm [rowoff * D_MODEL + d]);
        float dx = dltv * xv;
        #pragma unroll
        for (int s = 0; s < 16; ++s) {
            float dA  = __expf(fmaxf(dltv * Asv[s], -2.f));
            float dBu = clampf_(dx * Bsh[tt][s], -5.f, 5.f);
            h[s] = clampf_(fmaf(dA, h[s], dBu), -100.f, 100.f);
            ap[s] *= dA;
        }
    }
    const size_t off = (((size_t)b * NCHUNK + c) * D_STATE) * D_MODEL + d;
    #pragma unroll
    for (int s = 0; s < 16; ++s) {
        h_end[off + (size_t)s * D_MODEL] = h[s];
        Aprod[off + (size_t)s * D_MODEL] = ap[s];
    }
}

// pass B: carry propagation across chunks per (b,s,d)
__global__ __launch_bounds__(256) void k_scanB(const float* __restrict__ h_end,
                                               const float* __restrict__ Aprod,
                                               float* __restrict__ h_in) {
    const int idx = blockIdx.x * 256 + threadIdx.x;  // 4*16*768 = 49152
    const int d = idx % D_MODEL;
    const int rest = idx / D_MODEL;
    const int s = rest & 15, b = rest >> 4;
    float hc = 0.f;
    for (int c = 0; c < NCHUNK; ++c) {
        const size_t off = (((size_t)b * NCHUNK + c) * D_STATE + s) * D_MODEL + d;
        h_in[off] = hc;
        hc = Aprod[off] * hc + h_end[off];
    }
}

// pass C: replay with true carry, fuse y = clip(sum_s h*C) + xm*D, * gate -> bf16
__global__ __launch_bounds__(256) void k_scanC(const unsigned short* __restrict__ dlt,
                                               const unsigned short* __restrict__ xm,
                                               const float* __restrict__ Bm,
                                               const float* __restrict__ Cm,
                                               const float* __restrict__ A_cl,
                                               const float* __restrict__ h_in,
                                               const float* __restrict__ Dvec,
                                               const unsigned short* __restrict__ gate,
                                               unsigned short* __restrict__ ymid) {
    const int d = blockIdx.x * 256 + threadIdx.x;
    const int c = blockIdx.y, b = blockIdx.z;
    __shared__ float Bsh[LCH][D_STATE];
    __shared__ float Csh[LCH][D_STATE];
    const int rowbase = b * LL + c * LCH;
    for (int i = threadIdx.x; i < LCH * D_STATE; i += 256) {
        ((float*)Bsh)[i] = Bm[(size_t)rowbase * D_STATE + i];
        ((float*)Csh)[i] = Cm[(size_t)rowbase * D_STATE + i];
    }
    __syncthreads();

    float Asv[16], h[16];
    const size_t coff = (((size_t)b * NCHUNK + c) * D_STATE) * D_MODEL + d;
    #pragma unroll
    for (int s = 0; s < 16; ++s) {
        Asv[s] = A_cl[s * D_MODEL + d];
        h[s] = h_in[coff + (size_t)s * D_MODEL];
    }
    const float Dv = Dvec[d];
    for (int tt = 0; tt < LCH; ++tt) {
        const size_t rowoff = (size_t)(rowbase + tt);
        float dltv = bf2f(dlt[rowoff * D_MODEL + d]);
        float xv   = bf2f(xm [rowoff * D_MODEL + d]);
        float dx = dltv * xv;
        float y = 0.f;
        #pragma unroll
        for (int s = 0; s < 16; ++s) {
            float dA  = __expf(fmaxf(dltv * Asv[s], -2.f));
            float dBu = clampf_(dx * Bsh[tt][s], -5.f, 5.f);
            h[s] = clampf_(fmaf(dA, h[s], dBu), -100.f, 100.f);
            y = fmaf(h[s], Csh[tt][s], y);
        }
        y = clampf_(y, -10.f, 10.f);
        y = fmaf(xv, Dv, y);
        y *= bf2f(gate[rowoff * D_MODEL + d]);
        ymid[rowoff * D_MODEL + d] = f2bf(y);
    }
}

// ---------------- launch ----------------
extern "C" void kernel_launch(void* const* d_in, const int* in_sizes, int n_in,
                              void* d_out, int out_size, void* d_ws, size_t ws_size,
                              hipStream_t stream) {
    const float* x       = (const float*)d_in[0];
    const float* W_in    = (const float*)d_in[1];
    const float* b_in    = (const float*)d_in[2];
    const float* W_B     = (const float*)d_in[3];
    const float* b_B     = (const float*)d_in[4];
    const float* W_C     = (const float*)d_in[5];
    const float* b_C     = (const float*)d_in[6];
    const float* W_delta = (const float*)d_in[7];
    const float* b_delta = (const float*)d_in[8];
    const float* W_out   = (const float*)d_in[9];
    const float* b_out   = (const float*)d_in[10];
    const float* A_log   = (const float*)d_in[11];
    const float* Dvec    = (const float*)d_in[12];
    float* out = (float*)d_out;

    char* p = (char*)d_ws;
    auto alloc = [&](size_t bytes) {
        char* r = p;
        p += (bytes + 255) & ~(size_t)255;
        return r;
    };
    unsigned short* xb    = (unsigned short*)alloc((size_t)M_TOT * D_MODEL * 2);
    unsigned short* Wint  = (unsigned short*)alloc((size_t)2 * D_MODEL * D_MODEL * 2);
    unsigned short* WdBC  = (unsigned short*)alloc((size_t)N_DBC * D_MODEL * 2);
    unsigned short* Wot   = (unsigned short*)alloc((size_t)D_MODEL * D_MODEL * 2);
    float*          bdbc  = (float*)alloc((size_t)N_DBC * 4);
    unsigned short* xm_b  = (unsigned short*)alloc((size_t)M_TOT * D_MODEL * 2);
    unsigned short* gate_b= (unsigned short*)alloc((size_t)M_TOT * D_MODEL * 2);
    unsigned short* dlt_b = (unsigned short*)alloc((size_t)M_TOT * D_MODEL * 2);
    float*          Bm    = (float*)alloc((size_t)M_TOT * D_STATE * 4);
    float*          Cm    = (float*)alloc((size_t)M_TOT * D_STATE * 4);
    float*          A_cl  = (float*)alloc((size_t)D_STATE * D_MODEL * 4);
    float*          h_end = (float*)alloc((size_t)BB * NCHUNK * D_STATE * D_MODEL * 4);
    float*          Aprod = (float*)alloc((size_t)BB * NCHUNK * D_STATE * D_MODEL * 4);
    float*          h_in  = (float*)alloc((size_t)BB * NCHUNK * D_STATE * D_MODEL * 4);
    unsigned short* ymid  = (unsigned short*)alloc((size_t)M_TOT * D_MODEL * 2);

    // prep
    k_convert_x<<<(M_TOT * D_MODEL / 4 + 255) / 256, 256, 0, stream>>>(x, xb, M_TOT * D_MODEL / 4);
    k_prep_A<<<(D_STATE * D_MODEL + 255) / 256, 256, 0, stream>>>(A_log, A_cl, D_STATE * D_MODEL);
    k_transpose_bf16<<<dim3(2 * D_MODEL / 32, D_MODEL / 32), 256, 0, stream>>>(W_in, Wint, D_MODEL, 2 * D_MODEL);
    k_transpose_bf16<<<dim3(D_MODEL / 32, D_MODEL / 32), 256, 0, stream>>>(W_delta, WdBC, D_MODEL, D_MODEL);
    k_fill_bc<<<(128 * D_MODEL + 255) / 256, 256, 0, stream>>>(W_B, W_C, WdBC);
    k_bias_dbc<<<(N_DBC + 255) / 256, 256, 0, stream>>>(b_delta, b_B, b_C, bdbc);
    k_transpose_bf16<<<dim3(D_MODEL / 32, D_MODEL / 32), 256, 0, stream>>>(W_out, Wot, D_MODEL, D_MODEL);

    // in-proj GEMM + silu split; 1D grid: gx=12, 768 blocks
    k_gemm<0><<<dim3((2 * D_MODEL / 128) * (M_TOT / 128)), 256, 0, stream>>>(
        xb, Wint, b_in, 2 * D_MODEL / 128, nullptr, nullptr, xm_b, gate_b);
    // delta + B + C fused GEMM; gx=7, 448 blocks
    k_gemm<1><<<dim3((N_DBC / 128) * (M_TOT / 128)), 256, 0, stream>>>(
        xm_b, WdBC, bdbc, N_DBC / 128, Bm, Cm, dlt_b, nullptr);
    // chunked scan
    k_scanA<<<dim3(D_MODEL / 256, NCHUNK, BB), 256, 0, stream>>>(dlt_b, xm_b, Bm, A_cl, h_end, Aprod);
    k_scanB<<<(BB * D_STATE * D_MODEL) / 256, 256, 0, stream>>>(h_end, Aprod, h_in);
    k_scanC<<<dim3(D_MODEL / 256, NCHUNK, BB), 256, 0, stream>>>(
        dlt_b, xm_b, Bm, Cm, A_cl, h_in, Dvec, gate_b, ymid);
    // out-proj GEMM + clip; gx=6, 384 blocks
    k_gemm<2><<<dim3((D_MODEL / 128) * (M_TOT / 128)), 256, 0, stream>>>(
        ymid, Wot, b_out, D_MODEL / 128, out, nullptr, nullptr, nullptr);
}

// Round 11
// 209.851 us; speedup vs baseline: 1.0210x; 1.0210x over previous
//
#include <hip/hip_runtime.h>
#include <hip/hip_bf16.h>
#include <cstdint>
#include <cstddef>

#define D_MODEL 768
#define D_STATE 16
#define BB      4
#define LL      2048
#define M_TOT   (BB*LL)      // 8192
#define NCHUNK  64
#define LCH     (LL/NCHUNK)  // 32
#define N_DBC   896          // 768 delta + 16 B + 16 C + 96 pad
#define KC      768          // all GEMMs share K = D_MODEL
#define NTK     (KC/32)      // 24 K-steps

typedef __attribute__((ext_vector_type(8))) short bf16x8;
typedef __attribute__((ext_vector_type(4))) float f32x4;

__device__ __forceinline__ float clampf_(float x, float lo, float hi) {
    return fminf(fmaxf(x, lo), hi);
}
__device__ __forceinline__ float siluf_(float x) {
    return x / (1.f + __expf(-x));
}
// f32 -> bf16 round-to-nearest-even, as raw u16
__device__ __forceinline__ unsigned short f2bf(float f) {
    unsigned u = __float_as_uint(f);
    u += 0x7fffu + ((u >> 16) & 1u);
    return (unsigned short)(u >> 16);
}
__device__ __forceinline__ float bf2f(unsigned short u) {
    return __uint_as_float(((unsigned)u) << 16);
}
// async global->LDS, 16 bytes per lane; lds base must be wave-uniform
__device__ __forceinline__ void gload16(void* lds, const void* g) {
    __builtin_amdgcn_global_load_lds(
        (const __attribute__((address_space(1))) void*)g,
        (__attribute__((address_space(3))) void*)lds, 16, 0, 0);
}

// ---------------- prep kernels ----------------

__global__ __launch_bounds__(256) void k_convert_x(const float* __restrict__ x,
                                                   unsigned short* __restrict__ xb, int n4) {
    int i = blockIdx.x * 256 + threadIdx.x;
    if (i >= n4) return;
    float4 v = ((const float4*)x)[i];
    ushort4 o;
    o.x = f2bf(v.x); o.y = f2bf(v.y); o.z = f2bf(v.z); o.w = f2bf(v.w);
    ((ushort4*)xb)[i] = o;
}

__global__ __launch_bounds__(256) void k_prep_A(const float* __restrict__ A_log,
                                                float* __restrict__ A_cl, int n) {
    int i = blockIdx.x * 256 + threadIdx.x;
    if (i < n) A_cl[i] = clampf_(-__expf(A_log[i]), -5.f, -0.1f);
}

// transpose R x C f32 -> C x R bf16 (R,C multiples of 32); dst row stride = R
__global__ __launch_bounds__(256) void k_transpose_bf16(const float* __restrict__ src,
                                                        unsigned short* __restrict__ dst,
                                                        int R, int C) {
    __shared__ float tile[32][33];
    int tx = threadIdx.x & 31, ty = threadIdx.x >> 5;
    int c0 = blockIdx.x * 32, r0 = blockIdx.y * 32;
    #pragma unroll
    for (int rr = ty; rr < 32; rr += 8)
        tile[rr][tx] = src[(size_t)(r0 + rr) * C + c0 + tx];
    __syncthreads();
    #pragma unroll
    for (int rr = ty; rr < 32; rr += 8)
        dst[(size_t)(c0 + rr) * R + r0 + tx] = f2bf(tile[tx][rr]);
}

// rows 768..895 of WdBC: W_B^T, W_C^T, zero-pad
__global__ __launch_bounds__(256) void k_fill_bc(const float* __restrict__ W_B,
                                                 const float* __restrict__ W_C,
                                                 unsigned short* __restrict__ WdBC) {
    int idx = blockIdx.x * 256 + threadIdx.x;     // 128*768
    if (idx >= 128 * D_MODEL) return;
    int r = idx / D_MODEL + D_MODEL, k = idx % D_MODEL;
    unsigned short v = 0;
    if (r < D_MODEL + 16)       v = f2bf(W_B[k * 16 + (r - D_MODEL)]);
    else if (r < D_MODEL + 32)  v = f2bf(W_C[k * 16 + (r - D_MODEL - 16)]);
    WdBC[(size_t)r * D_MODEL + k] = v;
}

__global__ __launch_bounds__(256) void k_bias_dbc(const float* __restrict__ b_delta,
                                                  const float* __restrict__ b_B,
                                                  const float* __restrict__ b_C,
                                                  float* __restrict__ bias) {
    int i = blockIdx.x * 256 + threadIdx.x;
    if (i >= N_DBC) return;
    float v = 0.f;
    if (i < D_MODEL)            v = b_delta[i];
    else if (i < D_MODEL + 16)  v = b_B[i - D_MODEL];
    else if (i < D_MODEL + 32)  v = b_C[i - D_MODEL - 16];
    bias[i] = v;
}

// ---------------- main bf16 MFMA GEMM ----------------
// 256x128 tile, 8 waves (512 thr), 3-buffer counted-vmcnt pipeline,
// compile-time buffer indices, round-7 fence discipline, XCD swizzle. K=768.
// Staging: 3 x gload16 per thread per step (2 A-chunks + 1 B-chunk).
template<int EPI>
__global__ __launch_bounds__(512) void k_gemm(const unsigned short* __restrict__ A,
                                              const unsigned short* __restrict__ Bt,
                                              const float* __restrict__ bias,
                                              int gx,
                                              float* __restrict__ out_f,
                                              float* __restrict__ out_f2,
                                              unsigned short* __restrict__ out_b0,
                                              unsigned short* __restrict__ out_b1) {
    __shared__ __align__(16) unsigned short As0[256 * 32], As1[256 * 32], As2[256 * 32];
    __shared__ __align__(16) unsigned short Bs0[128 * 32], Bs1[128 * 32], Bs2[128 * 32];
    const int tid = threadIdx.x;
    const int wave = tid >> 6, lane = tid & 63;
    const int wm = wave >> 1, wn = wave & 1;   // wm 0..3 (rows), wn 0..1 (cols)

    // bijective XCD swizzle (m204, r==0 case); all grids here are %8==0
    const int nwg = gridDim.x;
    const int wg = blockIdx.x;
    int swz = wg;
    if ((nwg & 7) == 0) {
        const int q = nwg >> 3;
        swz = (wg & 7) * q + (wg >> 3);
    }
    const int bx = swz % gx, by = swz / gx;
    const int m0 = by * 256, n0 = bx * 128;
    const int lr = lane & 15, lk = (lane >> 4) * 8;

    // staging sources: A chunks ci = g*512 + tid (g=0,1), B chunk ci = tid
    // chunk ci -> row = ci>>2, k8 = (ci&3)*8 shorts
    const unsigned short* gA0 = &A [(size_t)(m0 +       (tid >> 2)) * KC + (tid & 3) * 8];
    const unsigned short* gA1 = &A [(size_t)(m0 + 128 + (tid >> 2)) * KC + (tid & 3) * 8];
    const unsigned short* gB0 = &Bt[(size_t)(n0 +       (tid >> 2)) * KC + (tid & 3) * 8];
    const int ldsA0 = (wave * 64) * 8;          // shorts, wave-uniform
    const int ldsA1 = (512 + wave * 64) * 8;
    const int ldsB0 = (wave * 64) * 8;

    f32x4 acc[4][4] = {};

    auto stageT = [&](unsigned short* Ab, unsigned short* Bb, int kt) {
        gload16(&Ab[ldsA0], gA0 + kt);
        gload16(&Ab[ldsA1], gA1 + kt);
        gload16(&Bb[ldsB0], gB0 + kt);
    };
    auto computeT = [&](const unsigned short* Ab, const unsigned short* Bb) {
        bf16x8 af[4], bfr[4];
        #pragma unroll
        for (int mt = 0; mt < 4; ++mt)
            af[mt] = *(const bf16x8*)&Ab[(wm * 64 + mt * 16 + lr) * 32 + lk];
        #pragma unroll
        for (int nt = 0; nt < 4; ++nt)
            bfr[nt] = *(const bf16x8*)&Bb[(wn * 64 + nt * 16 + lr) * 32 + lk];
        #pragma unroll
        for (int mt = 0; mt < 4; ++mt)
            #pragma unroll
            for (int nt = 0; nt < 4; ++nt)
                acc[mt][nt] = __builtin_amdgcn_mfma_f32_16x16x32_bf16(
                    af[mt], bfr[nt], acc[mt][nt], 0, 0, 0);
    };

    // prologue: tiles 0,1,2 in flight (9 outstanding); wait tile 0 -> vmcnt(6)
    stageT(As0, Bs0, 0);
    stageT(As1, Bs1, 32);
    stageT(As2, Bs2, 64);
    asm volatile("s_waitcnt vmcnt(6)" ::: "memory");
    __builtin_amdgcn_sched_barrier(0);
    __builtin_amdgcn_s_barrier();

#define SUBSTEP(Ab, Bb, t) do {                                   \
        computeT(Ab, Bb);                                         \
        asm volatile("s_waitcnt lgkmcnt(0)" ::: "memory");        \
        __builtin_amdgcn_sched_barrier(0);                        \
        __builtin_amdgcn_s_barrier();                             \
        stageT(Ab, Bb, ((t) + 3) << 5);                           \
        asm volatile("s_waitcnt vmcnt(6)" ::: "memory");          \
        __builtin_amdgcn_sched_barrier(0);                        \
        __builtin_amdgcn_s_barrier();                             \
    } while (0)

    // steady state: 7 iterations x 3 sub-steps = tiles 0..20, staging 3..23
    for (int t = 0; t < NTK - 3; t += 3) {
        SUBSTEP(As0, Bs0, t);
        SUBSTEP(As1, Bs1, t + 1);
        SUBSTEP(As2, Bs2, t + 2);
    }
#undef SUBSTEP
    // tail: tiles 21,22,23; drain 3 -> 0
    computeT(As0, Bs0);
    asm volatile("s_waitcnt vmcnt(3)" ::: "memory");
    __builtin_amdgcn_sched_barrier(0);
    __builtin_amdgcn_s_barrier();
    computeT(As1, Bs1);
    asm volatile("s_waitcnt vmcnt(0)" ::: "memory");
    __builtin_amdgcn_sched_barrier(0);
    __builtin_amdgcn_s_barrier();
    computeT(As2, Bs2);

    #pragma unroll
    for (int mt = 0; mt < 4; ++mt) {
        int row = m0 + wm * 64 + mt * 16 + (lane >> 4) * 4;
        #pragma unroll
        for (int nt = 0; nt < 4; ++nt) {
            int col = n0 + wn * 64 + nt * 16 + (lane & 15);
            #pragma unroll
            for (int i = 0; i < 4; ++i) {
                int r = row + i;
                float v = acc[mt][nt][i] + bias[col];
                if (EPI == 0) {
                    float s = siluf_(v);
                    if (col < D_MODEL) out_b0[(size_t)r * D_MODEL + col] = f2bf(s);
                    else               out_b1[(size_t)r * D_MODEL + (col - D_MODEL)] = f2bf(s);
                } else if (EPI == 1) {
                    if (col < D_MODEL) {
                        float sp = (v > 20.f) ? v : log1pf(__expf(v));
                        out_b0[(size_t)r * D_MODEL + col] = f2bf(clampf_(sp + 1e-4f, 1e-4f, 1.f));
                    } else if (col < D_MODEL + 16) {
                        out_f[(size_t)r * D_STATE + (col - D_MODEL)] = v;
                    } else if (col < D_MODEL + 32) {
                        out_f2[(size_t)r * D_STATE + (col - D_MODEL - 16)] = v;
                    }
                } else {
                    out_f[(size_t)r * D_MODEL + col] = clampf_(v, -10.f, 10.f);
                }
            }
        }
    }
}

// ---------------- chunked selective scan ----------------
// pass A: per (b, chunk, d) local scan from h=0; emit h_end, Aprod
__global__ __launch_bounds__(256) void k_scanA(const unsigned short* __restrict__ dlt,
                                               const unsigned short* __restrict__ xm,
                                               const float* __restrict__ Bm,
                                               const float* __restrict__ A_cl,
                                               float* __restrict__ h_end,
                                               float* __restrict__ Aprod) {
    const int d = blockIdx.x * 256 + threadIdx.x;
    const int c = blockIdx.y, b = blockIdx.z;
    __shared__ float Bsh[LCH][D_STATE];
    const int rowbase = b * LL + c * LCH;
    for (int i = threadIdx.x; i < LCH * D_STATE; i += 256)
        ((float*)Bsh)[i] = Bm[(size_t)rowbase * D_STATE + i];
    __syncthreads();

    float Asv[16], h[16], ap[16];
    #pragma unroll
    for (int s = 0; s < 16; ++s) {
        Asv[s] = A_cl[s * D_MODEL + d];
        h[s] = 0.f; ap[s] = 1.f;
    }
    for (int tt = 0; tt < LCH; ++tt) {
        const size_t rowoff = (size_t)(rowbase + tt);
        float dltv = bf2f(dlt[rowoff * D_MODEL + d]);
        float xv   = bf2f(xm [rowoff * D_MODEL + d]);
        float dx = dltv * xv;
        #pragma unroll
        for (int s = 0; s < 16; ++s) {
            float dA  = __expf(fmaxf(dltv * Asv[s], -2.f));
            float dBu = clampf_(dx * Bsh[tt][s], -5.f, 5.f);
            h[s] = clampf_(fmaf(dA, h[s], dBu), -100.f, 100.f);
            ap[s] *= dA;
        }
    }
    const size_t off = (((size_t)b * NCHUNK + c) * D_STATE) * D_MODEL + d;
    #pragma unroll
    for (int s = 0; s < 16; ++s) {
        h_end[off + (size_t)s * D_MODEL] = h[s];
        Aprod[off + (size_t)s * D_MODEL] = ap[s];
    }
}

// pass B: carry propagation across chunks per (b,s,d)
__global__ __launch_bounds__(256) void k_scanB(const float* __restrict__ h_end,
                                               const float* __restrict__ Aprod,
                                               float* __restrict__ h_in) {
    const int idx = blockIdx.x * 256 + threadIdx.x;  // 4*16*768 = 49152
    const int d = idx % D_MODEL;
    const int rest = idx / D_MODEL;
    const int s = rest & 15, b = rest >> 4;
    float hc = 0.f;
    for (int c = 0; c < NCHUNK; ++c) {
        const size_t off = (((size_t)b * NCHUNK + c) * D_STATE + s) * D_MODEL + d;
        h_in[off] = hc;
        hc = Aprod[off] * hc + h_end[off];
    }
}

// pass C: replay with true carry, fuse y = clip(sum_s h*C) + xm*D, * gate -> bf16
__global__ __launch_bounds__(256) void k_scanC(const unsigned short* __restrict__ dlt,
                                               const unsigned short* __restrict__ xm,
                                               const float* __restrict__ Bm,
                                               const float* __restrict__ Cm,
                                               const float* __restrict__ A_cl,
                                               const float* __restrict__ h_in,
                                               const float* __restrict__ Dvec,
                                               const unsigned short* __restrict__ gate,
                                               unsigned short* __restrict__ ymid) {
    const int d = blockIdx.x * 256 + threadIdx.x;
    const int c = blockIdx.y, b = blockIdx.z;
    __shared__ float Bsh[LCH][D_STATE];
    __shared__ float Csh[LCH][D_STATE];
    const int rowbase = b * LL + c * LCH;
    for (int i = threadIdx.x; i < LCH * D_STATE; i += 256) {
        ((float*)Bsh)[i] = Bm[(size_t)rowbase * D_STATE + i];
        ((float*)Csh)[i] = Cm[(size_t)rowbase * D_STATE + i];
    }
    __syncthreads();

    float Asv[16], h[16];
    const size_t coff = (((size_t)b * NCHUNK + c) * D_STATE) * D_MODEL + d;
    #pragma unroll
    for (int s = 0; s < 16; ++s) {
        Asv[s] = A_cl[s * D_MODEL + d];
        h[s] = h_in[coff + (size_t)s * D_MODEL];
    }
    const float Dv = Dvec[d];
    for (int tt = 0; tt < LCH; ++tt) {
        const size_t rowoff = (size_t)(rowbase + tt);
        float dltv = bf2f(dlt[rowoff * D_MODEL + d]);
        float xv   = bf2f(xm [rowoff * D_MODEL + d]);
        float dx = dltv * xv;
        float y = 0.f;
        #pragma unroll
        for (int s = 0; s < 16; ++s) {
            float dA  = __expf(fmaxf(dltv * Asv[s], -2.f));
            float dBu = clampf_(dx * Bsh[tt][s], -5.f, 5.f);
            h[s] = clampf_(fmaf(dA, h[s], dBu), -100.f, 100.f);
            y = fmaf(h[s], Csh[tt][s], y);
        }
        y = clampf_(y, -10.f, 10.f);
        y = fmaf(xv, Dv, y);
        y *= bf2f(gate[rowoff * D_MODEL + d]);
        ymid[rowoff * D_MODEL + d] = f2bf(y);
    }
}

// ---------------- launch ----------------
extern "C" void kernel_launch(void* const* d_in, const int* in_sizes, int n_in,
                              void* d_out, int out_size, void* d_ws, size_t ws_size,
                              hipStream_t stream) {
    const float* x       = (const float*)d_in[0];
    const float* W_in    = (const float*)d_in[1];
    const float* b_in    = (const float*)d_in[2];
    const float* W_B     = (const float*)d_in[3];
    const float* b_B     = (const float*)d_in[4];
    const float* W_C     = (const float*)d_in[5];
    const float* b_C     = (const float*)d_in[6];
    const float* W_delta = (const float*)d_in[7];
    const float* b_delta = (const float*)d_in[8];
    const float* W_out   = (const float*)d_in[9];
    const float* b_out   = (const float*)d_in[10];
    const float* A_log   = (const float*)d_in[11];
    const float* Dvec    = (const float*)d_in[12];
    float* out = (float*)d_out;

    char* p = (char*)d_ws;
    auto alloc = [&](size_t bytes) {
        char* r = p;
        p += (bytes + 255) & ~(size_t)255;
        return r;
    };
    unsigned short* xb    = (unsigned short*)alloc((size_t)M_TOT * D_MODEL * 2);
    unsigned short* Wint  = (unsigned short*)alloc((size_t)2 * D_MODEL * D_MODEL * 2);
    unsigned short* WdBC  = (unsigned short*)alloc((size_t)N_DBC * D_MODEL * 2);
    unsigned short* Wot   = (unsigned short*)alloc((size_t)D_MODEL * D_MODEL * 2);
    float*          bdbc  = (float*)alloc((size_t)N_DBC * 4);
    unsigned short* xm_b  = (unsigned short*)alloc((size_t)M_TOT * D_MODEL * 2);
    unsigned short* gate_b= (unsigned short*)alloc((size_t)M_TOT * D_MODEL * 2);
    unsigned short* dlt_b = (unsigned short*)alloc((size_t)M_TOT * D_MODEL * 2);
    float*          Bm    = (float*)alloc((size_t)M_TOT * D_STATE * 4);
    float*          Cm    = (float*)alloc((size_t)M_TOT * D_STATE * 4);
    float*          A_cl  = (float*)alloc((size_t)D_STATE * D_MODEL * 4);
    float*          h_end = (float*)alloc((size_t)BB * NCHUNK * D_STATE * D_MODEL * 4);
    float*          Aprod = (float*)alloc((size_t)BB * NCHUNK * D_STATE * D_MODEL * 4);
    float*          h_in  = (float*)alloc((size_t)BB * NCHUNK * D_STATE * D_MODEL * 4);
    unsigned short* ymid  = (unsigned short*)alloc((size_t)M_TOT * D_MODEL * 2);

    // prep
    k_convert_x<<<(M_TOT * D_MODEL / 4 + 255) / 256, 256, 0, stream>>>(x, xb, M_TOT * D_MODEL / 4);
    k_prep_A<<<(D_STATE * D_MODEL + 255) / 256, 256, 0, stream>>>(A_log, A_cl, D_STATE * D_MODEL);
    k_transpose_bf16<<<dim3(2 * D_MODEL / 32, D_MODEL / 32), 256, 0, stream>>>(W_in, Wint, D_MODEL, 2 * D_MODEL);
    k_transpose_bf16<<<dim3(D_MODEL / 32, D_MODEL / 32), 256, 0, stream>>>(W_delta, WdBC, D_MODEL, D_MODEL);
    k_fill_bc<<<(128 * D_MODEL + 255) / 256, 256, 0, stream>>>(W_B, W_C, WdBC);
    k_bias_dbc<<<(N_DBC + 255) / 256, 256, 0, stream>>>(b_delta, b_B, b_C, bdbc);
    k_transpose_bf16<<<dim3(D_MODEL / 32, D_MODEL / 32), 256, 0, stream>>>(W_out, Wot, D_MODEL, D_MODEL);

    // in-proj GEMM + silu split; gx=12, 12x32 = 384 blocks (512 thr)
    k_gemm<0><<<dim3((2 * D_MODEL / 128) * (M_TOT / 256)), 512, 0, stream>>>(
        xb, Wint, b_in, 2 * D_MODEL / 128, nullptr, nullptr, xm_b, gate_b);
    // delta + B + C fused GEMM; gx=7, 7x32 = 224 blocks
    k_gemm<1><<<dim3((N_DBC / 128) * (M_TOT / 256)), 512, 0, stream>>>(
        xm_b, WdBC, bdbc, N_DBC / 128, Bm, Cm, dlt_b, nullptr);
    // chunked scan
    k_scanA<<<dim3(D_MODEL / 256, NCHUNK, BB), 256, 0, stream>>>(dlt_b, xm_b, Bm, A_cl, h_end, Aprod);
    k_scanB<<<(BB * D_STATE * D_MODEL) / 256, 256, 0, stream>>>(h_end, Aprod, h_in);
    k_scanC<<<dim3(D_MODEL / 256, NCHUNK, BB), 256, 0, stream>>>(
        dlt_b, xm_b, Bm, Cm, A_cl, h_in, Dvec, gate_b, ymid);
    // out-proj GEMM + clip; gx=6, 6x32 = 192 blocks
    k_gemm<2><<<dim3((D_MODEL / 128) * (M_TOT / 256)), 512, 0, stream>>>(
        ymid, Wot, b_out, D_MODEL / 128, out, nullptr, nullptr, nullptr);
}

// Round 13
// 207.018 us; speedup vs baseline: 1.0350x; 1.0137x over previous
//
#include <hip/hip_runtime.h>
#include <hip/hip_bf16.h>
#include <cstdint>
#include <cstddef>

#define D_MODEL 768
#define D_STATE 16
#define BB      4
#define LL      2048
#define M_TOT   (BB*LL)      // 8192
#define NCHUNK  64
#define LCH     (LL/NCHUNK)  // 32
#define N_DBC   896          // 768 delta + 16 B + 16 C + 96 pad
#define KC      768          // all GEMMs share K = D_MODEL
#define NTK     (KC/32)      // 24 K-steps

typedef __attribute__((ext_vector_type(8))) short bf16x8;
typedef __attribute__((ext_vector_type(4))) float f32x4;

__device__ __forceinline__ float clampf_(float x, float lo, float hi) {
    return fminf(fmaxf(x, lo), hi);
}
__device__ __forceinline__ float siluf_(float x) {
    return x / (1.f + __expf(-x));
}
// f32 -> bf16 round-to-nearest-even, as raw u16
__device__ __forceinline__ unsigned short f2bf(float f) {
    unsigned u = __float_as_uint(f);
    u += 0x7fffu + ((u >> 16) & 1u);
    return (unsigned short)(u >> 16);
}
__device__ __forceinline__ float bf2f(unsigned short u) {
    return __uint_as_float(((unsigned)u) << 16);
}
// async global->LDS, 16 bytes per lane; lds base must be wave-uniform
__device__ __forceinline__ void gload16(void* lds, const void* g) {
    __builtin_amdgcn_global_load_lds(
        (const __attribute__((address_space(1))) void*)g,
        (__attribute__((address_space(3))) void*)lds, 16, 0, 0);
}

// ---------------- prep kernels ----------------

__global__ __launch_bounds__(256) void k_convert_x(const float* __restrict__ x,
                                                   unsigned short* __restrict__ xb, int n4) {
    int i = blockIdx.x * 256 + threadIdx.x;
    if (i >= n4) return;
    float4 v = ((const float4*)x)[i];
    ushort4 o;
    o.x = f2bf(v.x); o.y = f2bf(v.y); o.z = f2bf(v.z); o.w = f2bf(v.w);
    ((ushort4*)xb)[i] = o;
}

__global__ __launch_bounds__(256) void k_prep_A(const float* __restrict__ A_log,
                                                float* __restrict__ A_cl, int n) {
    int i = blockIdx.x * 256 + threadIdx.x;
    if (i < n) A_cl[i] = clampf_(-__expf(A_log[i]), -5.f, -0.1f);
}

// transpose R x C f32 -> C x R bf16 (R,C multiples of 32); dst row stride = R
__global__ __launch_bounds__(256) void k_transpose_bf16(const float* __restrict__ src,
                                                        unsigned short* __restrict__ dst,
                                                        int R, int C) {
    __shared__ float tile[32][33];
    int tx = threadIdx.x & 31, ty = threadIdx.x >> 5;
    int c0 = blockIdx.x * 32, r0 = blockIdx.y * 32;
    #pragma unroll
    for (int rr = ty; rr < 32; rr += 8)
        tile[rr][tx] = src[(size_t)(r0 + rr) * C + c0 + tx];
    __syncthreads();
    #pragma unroll
    for (int rr = ty; rr < 32; rr += 8)
        dst[(size_t)(c0 + rr) * R + r0 + tx] = f2bf(tile[tx][rr]);
}

// rows 768..895 of WdBC: W_B^T, W_C^T, zero-pad
__global__ __launch_bounds__(256) void k_fill_bc(const float* __restrict__ W_B,
                                                 const float* __restrict__ W_C,
                                                 unsigned short* __restrict__ WdBC) {
    int idx = blockIdx.x * 256 + threadIdx.x;     // 128*768
    if (idx >= 128 * D_MODEL) return;
    int r = idx / D_MODEL + D_MODEL, k = idx % D_MODEL;
    unsigned short v = 0;
    if (r < D_MODEL + 16)       v = f2bf(W_B[k * 16 + (r - D_MODEL)]);
    else if (r < D_MODEL + 32)  v = f2bf(W_C[k * 16 + (r - D_MODEL - 16)]);
    WdBC[(size_t)r * D_MODEL + k] = v;
}

__global__ __launch_bounds__(256) void k_bias_dbc(const float* __restrict__ b_delta,
                                                  const float* __restrict__ b_B,
                                                  const float* __restrict__ b_C,
                                                  float* __restrict__ bias) {
    int i = blockIdx.x * 256 + threadIdx.x;
    if (i >= N_DBC) return;
    float v = 0.f;
    if (i < D_MODEL)            v = b_delta[i];
    else if (i < D_MODEL + 16)  v = b_B[i - D_MODEL];
    else if (i < D_MODEL + 32)  v = b_C[i - D_MODEL - 16];
    bias[i] = v;
}

// ---------------- main bf16 MFMA GEMM ----------------
// 256x128 tile, 8 waves, 3-buffer counted-vmcnt pipeline, XCD swizzle, AND
// LDS XOR-swizzle (rule #21: pre-swizzled GLOBAL source + swizzled READ,
// linear DMA dest): k-chunk slot jj holds global chunk jj ^ ((row>>1)&3).
// 16-lane read groups then cover all 8 bank-slots of the 128B period 2x each
// -> 2-way (free, m136) instead of the 8-way stride-64B conflict.
template<int EPI>
__global__ __launch_bounds__(512) void k_gemm(const unsigned short* __restrict__ A,
                                              const unsigned short* __restrict__ Bt,
                                              const float* __restrict__ bias,
                                              int gx,
                                              float* __restrict__ out_f,
                                              float* __restrict__ out_f2,
                                              unsigned short* __restrict__ out_b0,
                                              unsigned short* __restrict__ out_b1) {
    __shared__ __align__(16) unsigned short As0[256 * 32], As1[256 * 32], As2[256 * 32];
    __shared__ __align__(16) unsigned short Bs0[128 * 32], Bs1[128 * 32], Bs2[128 * 32];
    const int tid = threadIdx.x;
    const int wave = tid >> 6, lane = tid & 63;
    const int wm = wave >> 1, wn = wave & 1;   // wm 0..3 (rows), wn 0..1 (cols)

    // bijective XCD swizzle (m204, r==0 case); all grids here are %8==0
    const int nwg = gridDim.x;
    const int wg = blockIdx.x;
    int swz = wg;
    if ((nwg & 7) == 0) {
        const int q = nwg >> 3;
        swz = (wg & 7) * q + (wg >> 3);
    }
    const int bx = swz % gx, by = swz / gx;
    const int m0 = by * 256, n0 = bx * 128;
    const int lr = lane & 15;

    // staging sources, k-chunk XOR-pre-swizzled:
    // slot chunk ci (row=ci>>2, jj=ci&3) must hold global chunk jg = jj ^ ((row>>1)&3)
    // = (tid&3) ^ ((tid>>3)&3) for both A-groups (row offsets 0/128 are ≡0 mod 4).
    const int jg = ((tid & 3) ^ ((tid >> 3) & 3));
    const unsigned short* gA0 = &A [(size_t)(m0 +       (tid >> 2)) * KC + jg * 8];
    const unsigned short* gA1 = &A [(size_t)(m0 + 128 + (tid >> 2)) * KC + jg * 8];
    const unsigned short* gB0 = &Bt[(size_t)(n0 +       (tid >> 2)) * KC + jg * 8];
    const int ldsA0 = (wave * 64) * 8;          // shorts, wave-uniform, linear dest
    const int ldsA1 = (512 + wave * 64) * 8;
    const int ldsB0 = (wave * 64) * 8;

    // read-side swizzled k-offset (shorts): logical chunk jlog = lane>>4 lives in
    // slot jlog ^ ((row>>1)&3); (row>>1)&3 == (lr>>1)&3 since row-base ≡ 0 mod 16.
    const int swzk = (((lane >> 4) ^ (lane >> 1)) & 3) * 8;

    f32x4 acc[4][4] = {};

    auto stageT = [&](unsigned short* Ab, unsigned short* Bb, int kt) {
        gload16(&Ab[ldsA0], gA0 + kt);
        gload16(&Ab[ldsA1], gA1 + kt);
        gload16(&Bb[ldsB0], gB0 + kt);
    };
    auto computeT = [&](const unsigned short* Ab, const unsigned short* Bb) {
        bf16x8 af[4], bfr[4];
        #pragma unroll
        for (int mt = 0; mt < 4; ++mt)
            af[mt] = *(const bf16x8*)&Ab[(wm * 64 + mt * 16 + lr) * 32 + swzk];
        #pragma unroll
        for (int nt = 0; nt < 4; ++nt)
            bfr[nt] = *(const bf16x8*)&Bb[(wn * 64 + nt * 16 + lr) * 32 + swzk];
        #pragma unroll
        for (int mt = 0; mt < 4; ++mt)
            #pragma unroll
            for (int nt = 0; nt < 4; ++nt)
                acc[mt][nt] = __builtin_amdgcn_mfma_f32_16x16x32_bf16(
                    af[mt], bfr[nt], acc[mt][nt], 0, 0, 0);
    };

    // prologue: tiles 0,1,2 in flight (9 outstanding); wait tile 0 -> vmcnt(6)
    stageT(As0, Bs0, 0);
    stageT(As1, Bs1, 32);
    stageT(As2, Bs2, 64);
    asm volatile("s_waitcnt vmcnt(6)" ::: "memory");
    __builtin_amdgcn_sched_barrier(0);
    __builtin_amdgcn_s_barrier();

#define SUBSTEP(Ab, Bb, t) do {                                   \
        computeT(Ab, Bb);                                         \
        asm volatile("s_waitcnt lgkmcnt(0)" ::: "memory");        \
        __builtin_amdgcn_sched_barrier(0);                        \
        __builtin_amdgcn_s_barrier();                             \
        stageT(Ab, Bb, ((t) + 3) << 5);                           \
        asm volatile("s_waitcnt vmcnt(6)" ::: "memory");          \
        __builtin_amdgcn_sched_barrier(0);                        \
        __builtin_amdgcn_s_barrier();                             \
    } while (0)

    // steady state: 7 iterations x 3 sub-steps = tiles 0..20, staging 3..23
    for (int t = 0; t < NTK - 3; t += 3) {
        SUBSTEP(As0, Bs0, t);
        SUBSTEP(As1, Bs1, t + 1);
        SUBSTEP(As2, Bs2, t + 2);
    }
#undef SUBSTEP
    // tail: tiles 21,22,23; drain 3 -> 0
    computeT(As0, Bs0);
    asm volatile("s_waitcnt vmcnt(3)" ::: "memory");
    __builtin_amdgcn_sched_barrier(0);
    __builtin_amdgcn_s_barrier();
    computeT(As1, Bs1);
    asm volatile("s_waitcnt vmcnt(0)" ::: "memory");
    __builtin_amdgcn_sched_barrier(0);
    __builtin_amdgcn_s_barrier();
    computeT(As2, Bs2);

    #pragma unroll
    for (int mt = 0; mt < 4; ++mt) {
        int row = m0 + wm * 64 + mt * 16 + (lane >> 4) * 4;
        #pragma unroll
        for (int nt = 0; nt < 4; ++nt) {
            int col = n0 + wn * 64 + nt * 16 + (lane & 15);
            #pragma unroll
            for (int i = 0; i < 4; ++i) {
                int r = row + i;
                float v = acc[mt][nt][i] + bias[col];
                if (EPI == 0) {
                    float s = siluf_(v);
                    if (col < D_MODEL) out_b0[(size_t)r * D_MODEL + col] = f2bf(s);
                    else               out_b1[(size_t)r * D_MODEL + (col - D_MODEL)] = f2bf(s);
                } else if (EPI == 1) {
                    if (col < D_MODEL) {
                        float sp = (v > 20.f) ? v : log1pf(__expf(v));
                        out_b0[(size_t)r * D_MODEL + col] = f2bf(clampf_(sp + 1e-4f, 1e-4f, 1.f));
                    } else if (col < D_MODEL + 16) {
                        out_f[(size_t)r * D_STATE + (col - D_MODEL)] = v;
                    } else if (col < D_MODEL + 32) {
                        out_f2[(size_t)r * D_STATE + (col - D_MODEL - 16)] = v;
                    }
                } else {
                    out_f[(size_t)r * D_MODEL + col] = clampf_(v, -10.f, 10.f);
                }
            }
        }
    }
}

// ---------------- chunked selective scan ----------------
// pass A: per (b, chunk, d) local scan from h=0; emit h_end, Aprod
__global__ __launch_bounds__(256) void k_scanA(const unsigned short* __restrict__ dlt,
                                               const unsigned short* __restrict__ xm,
                                               const float* __restrict__ Bm,
                                               const float* __restrict__ A_cl,
                                               float* __restrict__ h_end,
                                               float* __restrict__ Aprod) {
    const int d = blockIdx.x * 256 + threadIdx.x;
    const int c = blockIdx.y, b = blockIdx.z;
    __shared__ float Bsh[LCH][D_STATE];
    const int rowbase = b * LL + c * LCH;
    for (int i = threadIdx.x; i < LCH * D_STATE; i += 256)
        ((float*)Bsh)[i] = Bm[(size_t)rowbase * D_STATE + i];
    __syncthreads();

    float Asv[16], h[16], ap[16];
    #pragma unroll
    for (int s = 0; s < 16; ++s) {
        Asv[s] = A_cl[s * D_MODEL + d];
        h[s] = 0.f; ap[s] = 1.f;
    }
    for (int tt = 0; tt < LCH; ++tt) {
        const size_t rowoff = (size_t)(rowbase + tt);
        float dltv = bf2f(dlt[rowoff * D_MODEL + d]);
        float xv   = bf2f(xm [rowoff * D_MODEL + d]);
        float dx = dltv * xv;
        #pragma unroll
        for (int s = 0; s < 16; ++s) {
            float dA  = __expf(fmaxf(dltv * Asv[s], -2.f));
            float dBu = clampf_(dx * Bsh[tt][s], -5.f, 5.f);
            h[s] = clampf_(fmaf(dA, h[s], dBu), -100.f, 100.f);
            ap[s] *= dA;
        }
    }
    const size_t off = (((size_t)b * NCHUNK + c) * D_STATE) * D_MODEL + d;
    #pragma unroll
    for (int s = 0; s < 16; ++s) {
        h_end[off + (size_t)s * D_MODEL] = h[s];
        Aprod[off + (size_t)s * D_MODEL] = ap[s];
    }
}

// pass B: carry propagation across chunks per (b,s,d)
__global__ __launch_bounds__(256) void k_scanB(const float* __restrict__ h_end,
                                               const float* __restrict__ Aprod,
                                               float* __restrict__ h_in) {
    const int idx = blockIdx.x * 256 + threadIdx.x;  // 4*16*768 = 49152
    const int d = idx % D_MODEL;
    const int rest = idx / D_MODEL;
    const int s = rest & 15, b = rest >> 4;
    float hc = 0.f;
    for (int c = 0; c < NCHUNK; ++c) {
        const size_t off = (((size_t)b * NCHUNK + c) * D_STATE + s) * D_MODEL + d;
        h_in[off] = hc;
        hc = Aprod[off] * hc + h_end[off];
    }
}

// pass C: replay with true carry, fuse y = clip(sum_s h*C) + xm*D, * gate -> bf16
__global__ __launch_bounds__(256) void k_scanC(const unsigned short* __restrict__ dlt,
                                               const unsigned short* __restrict__ xm,
                                               const float* __restrict__ Bm,
                                               const float* __restrict__ Cm,
                                               const float* __restrict__ A_cl,
                                               const float* __restrict__ h_in,
                                               const float* __restrict__ Dvec,
                                               const unsigned short* __restrict__ gate,
                                               unsigned short* __restrict__ ymid) {
    const int d = blockIdx.x * 256 + threadIdx.x;
    const int c = blockIdx.y, b = blockIdx.z;
    __shared__ float Bsh[LCH][D_STATE];
    __shared__ float Csh[LCH][D_STATE];
    const int rowbase = b * LL + c * LCH;
    for (int i = threadIdx.x; i < LCH * D_STATE; i += 256) {
        ((float*)Bsh)[i] = Bm[(size_t)rowbase * D_STATE + i];
        ((float*)Csh)[i] = Cm[(size_t)rowbase * D_STATE + i];
    }
    __syncthreads();

    float Asv[16], h[16];
    const size_t coff = (((size_t)b * NCHUNK + c) * D_STATE) * D_MODEL + d;
    #pragma unroll
    for (int s = 0; s < 16; ++s) {
        Asv[s] = A_cl[s * D_MODEL + d];
        h[s] = h_in[coff + (size_t)s * D_MODEL];
    }
    const float Dv = Dvec[d];
    for (int tt = 0; tt < LCH; ++tt) {
        const size_t rowoff = (size_t)(rowbase + tt);
        float dltv = bf2f(dlt[rowoff * D_MODEL + d]);
        float xv   = bf2f(xm [rowoff * D_MODEL + d]);
        float dx = dltv * xv;
        float y = 0.f;
        #pragma unroll
        for (int s = 0; s < 16; ++s) {
            float dA  = __expf(fmaxf(dltv * Asv[s], -2.f));
            float dBu = clampf_(dx * Bsh[tt][s], -5.f, 5.f);
            h[s] = clampf_(fmaf(dA, h[s], dBu), -100.f, 100.f);
            y = fmaf(h[s], Csh[tt][s], y);
        }
        y = clampf_(y, -10.f, 10.f);
        y = fmaf(xv, Dv, y);
        y *= bf2f(gate[rowoff * D_MODEL + d]);
        ymid[rowoff * D_MODEL + d] = f2bf(y);
    }
}

// ---------------- launch ----------------
extern "C" void kernel_launch(void* const* d_in, const int* in_sizes, int n_in,
                              void* d_out, int out_size, void* d_ws, size_t ws_size,
                              hipStream_t stream) {
    const float* x       = (const float*)d_in[0];
    const float* W_in    = (const float*)d_in[1];
    const float* b_in    = (const float*)d_in[2];
    const float* W_B     = (const float*)d_in[3];
    const float* b_B     = (const float*)d_in[4];
    const float* W_C     = (const float*)d_in[5];
    const float* b_C     = (const float*)d_in[6];
    const float* W_delta = (const float*)d_in[7];
    const float* b_delta = (const float*)d_in[8];
    const float* W_out   = (const float*)d_in[9];
    const float* b_out   = (const float*)d_in[10];
    const float* A_log   = (const float*)d_in[11];
    const float* Dvec    = (const float*)d_in[12];
    float* out = (float*)d_out;

    char* p = (char*)d_ws;
    auto alloc = [&](size_t bytes) {
        char* r = p;
        p += (bytes + 255) & ~(size_t)255;
        return r;
    };
    unsigned short* xb    = (unsigned short*)alloc((size_t)M_TOT * D_MODEL * 2);
    unsigned short* Wint  = (unsigned short*)alloc((size_t)2 * D_MODEL * D_MODEL * 2);
    unsigned short* WdBC  = (unsigned short*)alloc((size_t)N_DBC * D_MODEL * 2);
    unsigned short* Wot   = (unsigned short*)alloc((size_t)D_MODEL * D_MODEL * 2);
    float*          bdbc  = (float*)alloc((size_t)N_DBC * 4);
    unsigned short* xm_b  = (unsigned short*)alloc((size_t)M_TOT * D_MODEL * 2);
    unsigned short* gate_b= (unsigned short*)alloc((size_t)M_TOT * D_MODEL * 2);
    unsigned short* dlt_b = (unsigned short*)alloc((size_t)M_TOT * D_MODEL * 2);
    float*          Bm    = (float*)alloc((size_t)M_TOT * D_STATE * 4);
    float*          Cm    = (float*)alloc((size_t)M_TOT * D_STATE * 4);
    float*          A_cl  = (float*)alloc((size_t)D_STATE * D_MODEL * 4);
    float*          h_end = (float*)alloc((size_t)BB * NCHUNK * D_STATE * D_MODEL * 4);
    float*          Aprod = (float*)alloc((size_t)BB * NCHUNK * D_STATE * D_MODEL * 4);
    float*          h_in  = (float*)alloc((size_t)BB * NCHUNK * D_STATE * D_MODEL * 4);
    unsigned short* ymid  = (unsigned short*)alloc((size_t)M_TOT * D_MODEL * 2);

    // prep
    k_convert_x<<<(M_TOT * D_MODEL / 4 + 255) / 256, 256, 0, stream>>>(x, xb, M_TOT * D_MODEL / 4);
    k_prep_A<<<(D_STATE * D_MODEL + 255) / 256, 256, 0, stream>>>(A_log, A_cl, D_STATE * D_MODEL);
    k_transpose_bf16<<<dim3(2 * D_MODEL / 32, D_MODEL / 32), 256, 0, stream>>>(W_in, Wint, D_MODEL, 2 * D_MODEL);
    k_transpose_bf16<<<dim3(D_MODEL / 32, D_MODEL / 32), 256, 0, stream>>>(W_delta, WdBC, D_MODEL, D_MODEL);
    k_fill_bc<<<(128 * D_MODEL + 255) / 256, 256, 0, stream>>>(W_B, W_C, WdBC);
    k_bias_dbc<<<(N_DBC + 255) / 256, 256, 0, stream>>>(b_delta, b_B, b_C, bdbc);
    k_transpose_bf16<<<dim3(D_MODEL / 32, D_MODEL / 32), 256, 0, stream>>>(W_out, Wot, D_MODEL, D_MODEL);

    // in-proj GEMM + silu split; gx=12, 12x32 = 384 blocks (512 thr)
    k_gemm<0><<<dim3((2 * D_MODEL / 128) * (M_TOT / 256)), 512, 0, stream>>>(
        xb, Wint, b_in, 2 * D_MODEL / 128, nullptr, nullptr, xm_b, gate_b);
    // delta + B + C fused GEMM; gx=7, 7x32 = 224 blocks
    k_gemm<1><<<dim3((N_DBC / 128) * (M_TOT / 256)), 512, 0, stream>>>(
        xm_b, WdBC, bdbc, N_DBC / 128, Bm, Cm, dlt_b, nullptr);
    // chunked scan
    k_scanA<<<dim3(D_MODEL / 256, NCHUNK, BB), 256, 0, stream>>>(dlt_b, xm_b, Bm, A_cl, h_end, Aprod);
    k_scanB<<<(BB * D_STATE * D_MODEL) / 256, 256, 0, stream>>>(h_end, Aprod, h_in);
    k_scanC<<<dim3(D_MODEL / 256, NCHUNK, BB), 256, 0, stream>>>(
        dlt_b, xm_b, Bm, Cm, A_cl, h_in, Dvec, gate_b, ymid);
    // out-proj GEMM + clip; gx=6, 6x32 = 192 blocks
    k_gemm<2><<<dim3((D_MODEL / 128) * (M_TOT / 256)), 512, 0, stream>>>(
        ymid, Wot, b_out, D_MODEL / 128, out, nullptr, nullptr, nullptr);
}

// Round 14
// 203.082 us; speedup vs baseline: 1.0551x; 1.0194x over previous
//
#include <hip/hip_runtime.h>
#include <hip/hip_bf16.h>
#include <cstdint>
#include <cstddef>

#define D_MODEL 768
#define D_STATE 16
#define BB      4
#define LL      2048
#define M_TOT   (BB*LL)      // 8192
#define NCHUNK  64
#define LCH     (LL/NCHUNK)  // 32
#define N_DBC   896          // 768 delta + 16 B + 16 C + 96 pad
#define KC      768          // all GEMMs share K = D_MODEL
#define NTK     (KC/32)      // 24 K-steps (even)

typedef __attribute__((ext_vector_type(8))) short bf16x8;
typedef __attribute__((ext_vector_type(4))) float f32x4;

__device__ __forceinline__ float clampf_(float x, float lo, float hi) {
    return fminf(fmaxf(x, lo), hi);
}
__device__ __forceinline__ float siluf_(float x) {
    return x / (1.f + __expf(-x));
}
// f32 -> bf16 round-to-nearest-even, as raw u16
__device__ __forceinline__ unsigned short f2bf(float f) {
    unsigned u = __float_as_uint(f);
    u += 0x7fffu + ((u >> 16) & 1u);
    return (unsigned short)(u >> 16);
}
__device__ __forceinline__ float bf2f(unsigned short u) {
    return __uint_as_float(((unsigned)u) << 16);
}

// ---------------- prep kernels ----------------

__global__ __launch_bounds__(256) void k_convert_x(const float* __restrict__ x,
                                                   unsigned short* __restrict__ xb, int n4) {
    int i = blockIdx.x * 256 + threadIdx.x;
    if (i >= n4) return;
    float4 v = ((const float4*)x)[i];
    ushort4 o;
    o.x = f2bf(v.x); o.y = f2bf(v.y); o.z = f2bf(v.z); o.w = f2bf(v.w);
    ((ushort4*)xb)[i] = o;
}

__global__ __launch_bounds__(256) void k_prep_A(const float* __restrict__ A_log,
                                                float* __restrict__ A_cl, int n) {
    int i = blockIdx.x * 256 + threadIdx.x;
    if (i < n) A_cl[i] = clampf_(-__expf(A_log[i]), -5.f, -0.1f);
}

// transpose R x C f32 -> C x R bf16 (R,C multiples of 32); dst row stride = R
__global__ __launch_bounds__(256) void k_transpose_bf16(const float* __restrict__ src,
                                                        unsigned short* __restrict__ dst,
                                                        int R, int C) {
    __shared__ float tile[32][33];
    int tx = threadIdx.x & 31, ty = threadIdx.x >> 5;
    int c0 = blockIdx.x * 32, r0 = blockIdx.y * 32;
    #pragma unroll
    for (int rr = ty; rr < 32; rr += 8)
        tile[rr][tx] = src[(size_t)(r0 + rr) * C + c0 + tx];
    __syncthreads();
    #pragma unroll
    for (int rr = ty; rr < 32; rr += 8)
        dst[(size_t)(c0 + rr) * R + r0 + tx] = f2bf(tile[tx][rr]);
}

// rows 768..895 of WdBC: W_B^T, W_C^T, zero-pad
__global__ __launch_bounds__(256) void k_fill_bc(const float* __restrict__ W_B,
                                                 const float* __restrict__ W_C,
                                                 unsigned short* __restrict__ WdBC) {
    int idx = blockIdx.x * 256 + threadIdx.x;     // 128*768
    if (idx >= 128 * D_MODEL) return;
    int r = idx / D_MODEL + D_MODEL, k = idx % D_MODEL;
    unsigned short v = 0;
    if (r < D_MODEL + 16)       v = f2bf(W_B[k * 16 + (r - D_MODEL)]);
    else if (r < D_MODEL + 32)  v = f2bf(W_C[k * 16 + (r - D_MODEL - 16)]);
    WdBC[(size_t)r * D_MODEL + k] = v;
}

__global__ __launch_bounds__(256) void k_bias_dbc(const float* __restrict__ b_delta,
                                                  const float* __restrict__ b_B,
                                                  const float* __restrict__ b_C,
                                                  float* __restrict__ bias) {
    int i = blockIdx.x * 256 + threadIdx.x;
    if (i >= N_DBC) return;
    float v = 0.f;
    if (i < D_MODEL)            v = b_delta[i];
    else if (i < D_MODEL + 16)  v = b_B[i - D_MODEL];
    else if (i < D_MODEL + 32)  v = b_C[i - D_MODEL - 16];
    bias[i] = v;
}

// ---------------- main bf16 MFMA GEMM ----------------
// 256x128 tile, 8 waves, REGISTER-STAGED (global->VGPR->ds_write, no
// global_load_lds DMA), 2 LDS buffers, ONE barrier per K-step, XOR-swizzled
// LDS (write & read sides), XCD swizzle. K=768, NTK even.
// Substep t: issue loads t+2 -> regs; compute(buf[t&1]); lgkm(0)+barrier
// (my reads done + my prior writes done); ds_write regs -> buf[t&1].
template<int EPI>
__global__ __launch_bounds__(512) void k_gemm(const unsigned short* __restrict__ A,
                                              const unsigned short* __restrict__ Bt,
                                              const float* __restrict__ bias,
                                              int gx,
                                              float* __restrict__ out_f,
                                              float* __restrict__ out_f2,
                                              unsigned short* __restrict__ out_b0,
                                              unsigned short* __restrict__ out_b1) {
    __shared__ __align__(16) unsigned short As0[256 * 32], As1[256 * 32];
    __shared__ __align__(16) unsigned short Bs0[128 * 32], Bs1[128 * 32];
    const int tid = threadIdx.x;
    const int wave = tid >> 6, lane = tid & 63;
    const int wm = wave >> 1, wn = wave & 1;   // wm 0..3 (rows), wn 0..1 (cols)

    // bijective XCD swizzle (m204, r==0 case); all grids here are %8==0
    const int nwg = gridDim.x;
    const int wg = blockIdx.x;
    int swz = wg;
    if ((nwg & 7) == 0) {
        const int q = nwg >> 3;
        swz = (wg & 7) * q + (wg >> 3);
    }
    const int bx = swz % gx, by = swz / gx;
    const int m0 = by * 256, n0 = bx * 128;
    const int lr = lane & 15;

    // staging: thread owns chunks (row0, jl), (row0+128, jl) of A and (row0, jl) of B
    const int row0 = tid >> 2, jl = tid & 3;
    const int jj = jl ^ ((row0 >> 1) & 3);        // XOR-swizzled k-slot
    const unsigned short* gA0 = &A [(size_t)(m0 +       row0) * KC + jl * 8];
    const unsigned short* gA1 = &A [(size_t)(m0 + 128 + row0) * KC + jl * 8];
    const unsigned short* gB0 = &Bt[(size_t)(n0 +       row0) * KC + jl * 8];
    const int wA0 = (row0 * 4 + jj) * 8;          // shorts; (row0+128)>>1 ≡ row0>>1 mod 4
    const int wA1 = ((row0 + 128) * 4 + jj) * 8;
    const int wB0 = (row0 * 4 + jj) * 8;

    // read-side swizzled k-offset (shorts): logical chunk lane>>4 lives in
    // slot (lane>>4) ^ ((row>>1)&3), and (row>>1)&3 == (lr>>1)&3.
    const int swzk = (((lane >> 4) ^ (lane >> 1)) & 3) * 8;

    f32x4 acc[4][4] = {};
    float4 ra0, ra1, rb0;

    auto loadT = [&](int kt) {
        ra0 = *(const float4*)(gA0 + kt);
        ra1 = *(const float4*)(gA1 + kt);
        rb0 = *(const float4*)(gB0 + kt);
    };
    auto writeT = [&](unsigned short* Ab, unsigned short* Bb) {
        *(float4*)&Ab[wA0] = ra0;
        *(float4*)&Ab[wA1] = ra1;
        *(float4*)&Bb[wB0] = rb0;
    };
    auto computeT = [&](const unsigned short* Ab, const unsigned short* Bb) {
        bf16x8 af[4], bfr[4];
        #pragma unroll
        for (int mt = 0; mt < 4; ++mt)
            af[mt] = *(const bf16x8*)&Ab[(wm * 64 + mt * 16 + lr) * 32 + swzk];
        #pragma unroll
        for (int nt = 0; nt < 4; ++nt)
            bfr[nt] = *(const bf16x8*)&Bb[(wn * 64 + nt * 16 + lr) * 32 + swzk];
        #pragma unroll
        for (int mt = 0; mt < 4; ++mt)
            #pragma unroll
            for (int nt = 0; nt < 4; ++nt)
                acc[mt][nt] = __builtin_amdgcn_mfma_f32_16x16x32_bf16(
                    af[mt], bfr[nt], acc[mt][nt], 0, 0, 0);
    };

    // prologue: tiles 0 and 1 into buf0/buf1 (compiler inserts vmcnt waits)
    loadT(0);
    writeT(As0, Bs0);
    loadT(32);
    writeT(As1, Bs1);
    asm volatile("s_waitcnt lgkmcnt(0)" ::: "memory");
    __builtin_amdgcn_sched_barrier(0);
    __builtin_amdgcn_s_barrier();
    __builtin_amdgcn_sched_barrier(0);

#define SUBSTEP(Ab, Bb, t) do {                                   \
        if ((t) + 2 < NTK) loadT(((t) + 2) << 5);                 \
        computeT(Ab, Bb);                                         \
        asm volatile("s_waitcnt lgkmcnt(0)" ::: "memory");        \
        __builtin_amdgcn_sched_barrier(0);                        \
        __builtin_amdgcn_s_barrier();                             \
        __builtin_amdgcn_sched_barrier(0);                        \
        if ((t) + 2 < NTK) writeT(Ab, Bb);                        \
    } while (0)

    for (int t = 0; t < NTK; t += 2) {
        SUBSTEP(As0, Bs0, t);
        SUBSTEP(As1, Bs1, t + 1);
    }
#undef SUBSTEP

    #pragma unroll
    for (int mt = 0; mt < 4; ++mt) {
        int row = m0 + wm * 64 + mt * 16 + (lane >> 4) * 4;
        #pragma unroll
        for (int nt = 0; nt < 4; ++nt) {
            int col = n0 + wn * 64 + nt * 16 + (lane & 15);
            #pragma unroll
            for (int i = 0; i < 4; ++i) {
                int r = row + i;
                float v = acc[mt][nt][i] + bias[col];
                if (EPI == 0) {
                    float s = siluf_(v);
                    if (col < D_MODEL) out_b0[(size_t)r * D_MODEL + col] = f2bf(s);
                    else               out_b1[(size_t)r * D_MODEL + (col - D_MODEL)] = f2bf(s);
                } else if (EPI == 1) {
                    if (col < D_MODEL) {
                        float sp = (v > 20.f) ? v : log1pf(__expf(v));
                        out_b0[(size_t)r * D_MODEL + col] = f2bf(clampf_(sp + 1e-4f, 1e-4f, 1.f));
                    } else if (col < D_MODEL + 16) {
                        out_f[(size_t)r * D_STATE + (col - D_MODEL)] = v;
                    } else if (col < D_MODEL + 32) {
                        out_f2[(size_t)r * D_STATE + (col - D_MODEL - 16)] = v;
                    }
                } else {
                    out_f[(size_t)r * D_MODEL + col] = clampf_(v, -10.f, 10.f);
                }
            }
        }
    }
}

// ---------------- chunked selective scan ----------------
// pass A: per (b, chunk, d) local scan from h=0; emit h_end, Aprod
__global__ __launch_bounds__(256) void k_scanA(const unsigned short* __restrict__ dlt,
                                               const unsigned short* __restrict__ xm,
                                               const float* __restrict__ Bm,
                                               const float* __restrict__ A_cl,
                                               float* __restrict__ h_end,
                                               float* __restrict__ Aprod) {
    const int d = blockIdx.x * 256 + threadIdx.x;
    const int c = blockIdx.y, b = blockIdx.z;
    __shared__ float Bsh[LCH][D_STATE];
    const int rowbase = b * LL + c * LCH;
    for (int i = threadIdx.x; i < LCH * D_STATE; i += 256)
        ((float*)Bsh)[i] = Bm[(size_t)rowbase * D_STATE + i];
    __syncthreads();

    float Asv[16], h[16], ap[16];
    #pragma unroll
    for (int s = 0; s < 16; ++s) {
        Asv[s] = A_cl[s * D_MODEL + d];
        h[s] = 0.f; ap[s] = 1.f;
    }
    for (int tt = 0; tt < LCH; ++tt) {
        const size_t rowoff = (size_t)(rowbase + tt);
        float dltv = bf2f(dlt[rowoff * D_MODEL + d]);
        float xv   = bf2f(xm [rowoff * D_MODEL + d]);
        float dx = dltv * xv;
        #pragma unroll
        for (int s = 0; s < 16; ++s) {
            float dA  = __expf(fmaxf(dltv * Asv[s], -2.f));
            float dBu = clampf_(dx * Bsh[tt][s], -5.f, 5.f);
            h[s] = clampf_(fmaf(dA, h[s], dBu), -100.f, 100.f);
            ap[s] *= dA;
        }
    }
    const size_t off = (((size_t)b * NCHUNK + c) * D_STATE) * D_MODEL + d;
    #pragma unroll
    for (int s = 0; s < 16; ++s) {
        h_end[off + (size_t)s * D_MODEL] = h[s];
        Aprod[off + (size_t)s * D_MODEL] = ap[s];
    }
}

// pass B: carry propagation across chunks per (b,s,d)
__global__ __launch_bounds__(256) void k_scanB(const float* __restrict__ h_end,
                                               const float* __restrict__ Aprod,
                                               float* __restrict__ h_in) {
    const int idx = blockIdx.x * 256 + threadIdx.x;  // 4*16*768 = 49152
    const int d = idx % D_MODEL;
    const int rest = idx / D_MODEL;
    const int s = rest & 15, b = rest >> 4;
    float hc = 0.f;
    for (int c = 0; c < NCHUNK; ++c) {
        const size_t off = (((size_t)b * NCHUNK + c) * D_STATE + s) * D_MODEL + d;
        h_in[off] = hc;
        hc = Aprod[off] * hc + h_end[off];
    }
}

// pass C: replay with true carry, fuse y = clip(sum_s h*C) + xm*D, * gate -> bf16
__global__ __launch_bounds__(256) void k_scanC(const unsigned short* __restrict__ dlt,
                                               const unsigned short* __restrict__ xm,
                                               const float* __restrict__ Bm,
                                               const float* __restrict__ Cm,
                                               const float* __restrict__ A_cl,
                                               const float* __restrict__ h_in,
                                               const float* __restrict__ Dvec,
                                               const unsigned short* __restrict__ gate,
                                               unsigned short* __restrict__ ymid) {
    const int d = blockIdx.x * 256 + threadIdx.x;
    const int c = blockIdx.y, b = blockIdx.z;
    __shared__ float Bsh[LCH][D_STATE];
    __shared__ float Csh[LCH][D_STATE];
    const int rowbase = b * LL + c * LCH;
    for (int i = threadIdx.x; i < LCH * D_STATE; i += 256) {
        ((float*)Bsh)[i] = Bm[(size_t)rowbase * D_STATE + i];
        ((float*)Csh)[i] = Cm[(size_t)rowbase * D_STATE + i];
    }
    __syncthreads();

    float Asv[16], h[16];
    const size_t coff = (((size_t)b * NCHUNK + c) * D_STATE) * D_MODEL + d;
    #pragma unroll
    for (int s = 0; s < 16; ++s) {
        Asv[s] = A_cl[s * D_MODEL + d];
        h[s] = h_in[coff + (size_t)s * D_MODEL];
    }
    const float Dv = Dvec[d];
    for (int tt = 0; tt < LCH; ++tt) {
        const size_t rowoff = (size_t)(rowbase + tt);
        float dltv = bf2f(dlt[rowoff * D_MODEL + d]);
        float xv   = bf2f(xm [rowoff * D_MODEL + d]);
        float dx = dltv * xv;
        float y = 0.f;
        #pragma unroll
        for (int s = 0; s < 16; ++s) {
            float dA  = __expf(fmaxf(dltv * Asv[s], -2.f));
            float dBu = clampf_(dx * Bsh[tt][s], -5.f, 5.f);
            h[s] = clampf_(fmaf(dA, h[s], dBu), -100.f, 100.f);
            y = fmaf(h[s], Csh[tt][s], y);
        }
        y = clampf_(y, -10.f, 10.f);
        y = fmaf(xv, Dv, y);
        y *= bf2f(gate[rowoff * D_MODEL + d]);
        ymid[rowoff * D_MODEL + d] = f2bf(y);
    }
}

// ---------------- launch ----------------
extern "C" void kernel_launch(void* const* d_in, const int* in_sizes, int n_in,
                              void* d_out, int out_size, void* d_ws, size_t ws_size,
                              hipStream_t stream) {
    const float* x       = (const float*)d_in[0];
    const float* W_in    = (const float*)d_in[1];
    const float* b_in    = (const float*)d_in[2];
    const float* W_B     = (const float*)d_in[3];
    const float* b_B     = (const float*)d_in[4];
    const float* W_C     = (const float*)d_in[5];
    const float* b_C     = (const float*)d_in[6];
    const float* W_delta = (const float*)d_in[7];
    const float* b_delta = (const float*)d_in[8];
    const float* W_out   = (const float*)d_in[9];
    const float* b_out   = (const float*)d_in[10];
    const float* A_log   = (const float*)d_in[11];
    const float* Dvec    = (const float*)d_in[12];
    float* out = (float*)d_out;

    char* p = (char*)d_ws;
    auto alloc = [&](size_t bytes) {
        char* r = p;
        p += (bytes + 255) & ~(size_t)255;
        return r;
    };
    unsigned short* xb    = (unsigned short*)alloc((size_t)M_TOT * D_MODEL * 2);
    unsigned short* Wint  = (unsigned short*)alloc((size_t)2 * D_MODEL * D_MODEL * 2);
    unsigned short* WdBC  = (unsigned short*)alloc((size_t)N_DBC * D_MODEL * 2);
    unsigned short* Wot   = (unsigned short*)alloc((size_t)D_MODEL * D_MODEL * 2);
    float*          bdbc  = (float*)alloc((size_t)N_DBC * 4);
    unsigned short* xm_b  = (unsigned short*)alloc((size_t)M_TOT * D_MODEL * 2);
    unsigned short* gate_b= (unsigned short*)alloc((size_t)M_TOT * D_MODEL * 2);
    unsigned short* dlt_b = (unsigned short*)alloc((size_t)M_TOT * D_MODEL * 2);
    float*          Bm    = (float*)alloc((size_t)M_TOT * D_STATE * 4);
    float*          Cm    = (float*)alloc((size_t)M_TOT * D_STATE * 4);
    float*          A_cl  = (float*)alloc((size_t)D_STATE * D_MODEL * 4);
    float*          h_end = (float*)alloc((size_t)BB * NCHUNK * D_STATE * D_MODEL * 4);
    float*          Aprod = (float*)alloc((size_t)BB * NCHUNK * D_STATE * D_MODEL * 4);
    float*          h_in  = (float*)alloc((size_t)BB * NCHUNK * D_STATE * D_MODEL * 4);
    unsigned short* ymid  = (unsigned short*)alloc((size_t)M_TOT * D_MODEL * 2);

    // prep
    k_convert_x<<<(M_TOT * D_MODEL / 4 + 255) / 256, 256, 0, stream>>>(x, xb, M_TOT * D_MODEL / 4);
    k_prep_A<<<(D_STATE * D_MODEL + 255) / 256, 256, 0, stream>>>(A_log, A_cl, D_STATE * D_MODEL);
    k_transpose_bf16<<<dim3(2 * D_MODEL / 32, D_MODEL / 32), 256, 0, stream>>>(W_in, Wint, D_MODEL, 2 * D_MODEL);
    k_transpose_bf16<<<dim3(D_MODEL / 32, D_MODEL / 32), 256, 0, stream>>>(W_delta, WdBC, D_MODEL, D_MODEL);
    k_fill_bc<<<(128 * D_MODEL + 255) / 256, 256, 0, stream>>>(W_B, W_C, WdBC);
    k_bias_dbc<<<(N_DBC + 255) / 256, 256, 0, stream>>>(b_delta, b_B, b_C, bdbc);
    k_transpose_bf16<<<dim3(D_MODEL / 32, D_MODEL / 32), 256, 0, stream>>>(W_out, Wot, D_MODEL, D_MODEL);

    // in-proj GEMM + silu split; gx=12, 12x32 = 384 blocks (512 thr)
    k_gemm<0><<<dim3((2 * D_MODEL / 128) * (M_TOT / 256)), 512, 0, stream>>>(
        xb, Wint, b_in, 2 * D_MODEL / 128, nullptr, nullptr, xm_b, gate_b);
    // delta + B + C fused GEMM; gx=7, 7x32 = 224 blocks
    k_gemm<1><<<dim3((N_DBC / 128) * (M_TOT / 256)), 512, 0, stream>>>(
        xm_b, WdBC, bdbc, N_DBC / 128, Bm, Cm, dlt_b, nullptr);
    // chunked scan
    k_scanA<<<dim3(D_MODEL / 256, NCHUNK, BB), 256, 0, stream>>>(dlt_b, xm_b, Bm, A_cl, h_end, Aprod);
    k_scanB<<<(BB * D_STATE * D_MODEL) / 256, 256, 0, stream>>>(h_end, Aprod, h_in);
    k_scanC<<<dim3(D_MODEL / 256, NCHUNK, BB), 256, 0, stream>>>(
        dlt_b, xm_b, Bm, Cm, A_cl, h_in, Dvec, gate_b, ymid);
    // out-proj GEMM + clip; gx=6, 6x32 = 192 blocks
    k_gemm<2><<<dim3((D_MODEL / 128) * (M_TOT / 256)), 512, 0, stream>>>(
        ymid, Wot, b_out, D_MODEL / 128, out, nullptr, nullptr, nullptr);
}